// Round 1
// baseline (577.881 us; speedup 1.0000x reference)
//
#include <hip/hip_runtime.h>
#include <math.h>

// Problem constants (fixed shapes from reference)
#define B_   64
#define T_   2048
#define ENC_ 512
#define U_   128

// ---------------------------------------------------------------------------
// Kernel A: q'[b][u] = dh[b,:] @ Wa[:,u] + ba[u] + bb[u]
//   (bb folded here so the score epilogue only needs q'+k; bv dropped — it
//    cancels in softmax over T)
// ---------------------------------------------------------------------------
__global__ void qproj_kernel(const float* __restrict__ dh,
                             const float* __restrict__ Wa,
                             const float* __restrict__ ba,
                             const float* __restrict__ bb,
                             float* __restrict__ q) {
    const int b = blockIdx.x;      // 64 blocks
    const int u = threadIdx.x;     // 128 threads
    const float* dhb = dh + b * ENC_;   // DEC == 512
    float acc = 0.f;
#pragma unroll 8
    for (int e = 0; e < ENC_; ++e) {
        acc += dhb[e] * Wa[e * U_ + u];   // coalesced across u
    }
    q[b * U_ + u] = acc + ba[u] + bb[u];
}

// ---------------------------------------------------------------------------
// Kernel B: fused score GEMM.
//   scores[b,t] = sum_u tanh(q'[b,u] + (enc[b,t,:] @ Wb[:,u])) * Wv[u]
// Tile: 128 rows (m = b*T+t) x 128 cols (full U), BK=32.
// 256 threads, 8x8 register tile each. A staged transposed in LDS (stride
// 132 to break bank conflicts), Wb chunk staged as-is.
// ---------------------------------------------------------------------------
#define MBLK 128
#define BK   32
#define ASTR 132   // 128 + 4 pad

__global__ __launch_bounds__(256)
void score_kernel(const float* __restrict__ enc,
                  const float* __restrict__ Wb,
                  const float* __restrict__ q,
                  const float* __restrict__ Wv,
                  float* __restrict__ scores) {
    __shared__ float As[BK * ASTR];    // As[kk][row]  (transposed)
    __shared__ float Bs[BK * U_];      // Bs[kk][u]

    const int tid = threadIdx.x;
    const int tx  = tid & 15;          // col group: u = tx*8 + j
    const int ty  = tid >> 4;          // row group: row = ty*8 + i
    const int m0  = blockIdx.x * MBLK; // 1024 blocks
    const int b   = m0 >> 11;          // m0 / 2048 (uniform per block)
    const float* encBase = enc + (size_t)m0 * ENC_;

    float acc[8][8] = {};

    for (int kc = 0; kc < ENC_; kc += BK) {
        // ---- stage A chunk (128 rows x 32 k), transposed into LDS ----
#pragma unroll
        for (int i4 = 0; i4 < 4; ++i4) {
            const int flat = i4 * 256 + tid;
            const int row  = flat >> 3;      // 0..127
            const int c    = flat & 7;       // which float4 along k
            const float4 v = *(const float4*)(encBase + (size_t)row * ENC_ + kc + c * 4);
            As[(c * 4 + 0) * ASTR + row] = v.x;
            As[(c * 4 + 1) * ASTR + row] = v.y;
            As[(c * 4 + 2) * ASTR + row] = v.z;
            As[(c * 4 + 3) * ASTR + row] = v.w;
        }
        // ---- stage Wb chunk (32 k x 128 u) ----
#pragma unroll
        for (int i4 = 0; i4 < 4; ++i4) {
            const int flat = i4 * 256 + tid;
            const int kk   = flat >> 5;      // 0..31
            const int u4   = flat & 31;      // float4 index along u
            *(float4*)(&Bs[kk * U_ + u4 * 4]) =
                *(const float4*)(Wb + (size_t)(kc + kk) * U_ + u4 * 4);
        }
        __syncthreads();

#pragma unroll 4
        for (int kk = 0; kk < BK; ++kk) {
            const float4 a0 = *(const float4*)(&As[kk * ASTR + ty * 8]);
            const float4 a1 = *(const float4*)(&As[kk * ASTR + ty * 8 + 4]);
            const float4 b0 = *(const float4*)(&Bs[kk * U_ + tx * 8]);
            const float4 b1 = *(const float4*)(&Bs[kk * U_ + tx * 8 + 4]);
            const float av[8] = {a0.x, a0.y, a0.z, a0.w, a1.x, a1.y, a1.z, a1.w};
            const float bv[8] = {b0.x, b0.y, b0.z, b0.w, b1.x, b1.y, b1.z, b1.w};
#pragma unroll
            for (int i = 0; i < 8; ++i)
#pragma unroll
                for (int j = 0; j < 8; ++j)
                    acc[i][j] += av[i] * bv[j];
        }
        __syncthreads();
    }

    // ---- fused epilogue: score contribution + cross-lane reduction ----
    float qv[8], wv[8];
    {
        const float4 q0 = *(const float4*)(q + b * U_ + tx * 8);
        const float4 q1 = *(const float4*)(q + b * U_ + tx * 8 + 4);
        qv[0]=q0.x; qv[1]=q0.y; qv[2]=q0.z; qv[3]=q0.w;
        qv[4]=q1.x; qv[5]=q1.y; qv[6]=q1.z; qv[7]=q1.w;
        const float4 w0 = *(const float4*)(Wv + tx * 8);
        const float4 w1 = *(const float4*)(Wv + tx * 8 + 4);
        wv[0]=w0.x; wv[1]=w0.y; wv[2]=w0.z; wv[3]=w0.w;
        wv[4]=w1.x; wv[5]=w1.y; wv[6]=w1.z; wv[7]=w1.w;
    }
#pragma unroll
    for (int i = 0; i < 8; ++i) {
        float s = 0.f;
#pragma unroll
        for (int j = 0; j < 8; ++j)
            s += tanhf(qv[j] + acc[i][j]) * wv[j];
        // reduce over the 16 tx lanes (bits 0..3 of the lane id)
        s += __shfl_xor(s, 1, 64);
        s += __shfl_xor(s, 2, 64);
        s += __shfl_xor(s, 4, 64);
        s += __shfl_xor(s, 8, 64);
        if (tx == 0) scores[m0 + ty * 8 + i] = s;
    }
}

// ---------------------------------------------------------------------------
// Kernel C: softmax over T per batch. One block per b, 256 threads x 8 vals.
// Writes attn directly into d_out (after the context region).
// ---------------------------------------------------------------------------
__global__ void softmax_kernel(const float* __restrict__ scores,
                               float* __restrict__ attn) {
    const int b   = blockIdx.x;
    const int tid = threadIdx.x;
    const float* s = scores + b * T_;

    float v[8];
    float mx = -1e30f;
#pragma unroll
    for (int i = 0; i < 8; ++i) {
        v[i] = s[tid + i * 256];
        mx = fmaxf(mx, v[i]);
    }
    for (int off = 1; off < 64; off <<= 1)
        mx = fmaxf(mx, __shfl_xor(mx, off, 64));
    __shared__ float redm[4];
    __shared__ float reds[4];
    if ((tid & 63) == 0) redm[tid >> 6] = mx;
    __syncthreads();
    mx = fmaxf(fmaxf(redm[0], redm[1]), fmaxf(redm[2], redm[3]));

    float sum = 0.f;
#pragma unroll
    for (int i = 0; i < 8; ++i) {
        v[i] = expf(v[i] - mx);
        sum += v[i];
    }
    for (int off = 1; off < 64; off <<= 1)
        sum += __shfl_xor(sum, off, 64);
    if ((tid & 63) == 0) reds[tid >> 6] = sum;
    __syncthreads();
    sum = reds[0] + reds[1] + reds[2] + reds[3];
    const float inv = 1.f / sum;
#pragma unroll
    for (int i = 0; i < 8; ++i)
        attn[b * T_ + tid + i * 256] = v[i] * inv;
}

// ---------------------------------------------------------------------------
// Kernel D: context partials. Grid (8 t-chunks, 64 b). Each block streams
// 256 t-rows of enc and accumulates attn-weighted sums for all 512 e.
// ---------------------------------------------------------------------------
__global__ void context_partial_kernel(const float* __restrict__ enc,
                                       const float* __restrict__ attn,
                                       float* __restrict__ part) {
    const int ch  = blockIdx.x;   // 0..7
    const int b   = blockIdx.y;   // 0..63
    const int tid = threadIdx.x;  // 256

    __shared__ float aw[256];
    aw[tid] = attn[b * T_ + ch * 256 + tid];
    __syncthreads();

    const float* ebase = enc + ((size_t)b * T_ + ch * 256) * ENC_;
    float a0 = 0.f, a1 = 0.f;
#pragma unroll 4
    for (int t = 0; t < 256; ++t) {
        const float w = aw[t];
        a0 += w * ebase[(size_t)t * ENC_ + tid];
        a1 += w * ebase[(size_t)t * ENC_ + tid + 256];
    }
    float* p = part + ((size_t)ch * B_ + b) * ENC_;
    p[tid]       = a0;
    p[tid + 256] = a1;
}

// ---------------------------------------------------------------------------
// Kernel E: reduce the 8 chunk partials into context (start of d_out).
// ---------------------------------------------------------------------------
__global__ void context_reduce_kernel(const float* __restrict__ part,
                                      float* __restrict__ ctx) {
    const int idx = blockIdx.x * 256 + threadIdx.x;  // 0..32767
    float s = 0.f;
#pragma unroll
    for (int ch = 0; ch < 8; ++ch)
        s += part[(size_t)ch * (B_ * ENC_) + idx];
    ctx[idx] = s;
}

// ---------------------------------------------------------------------------
extern "C" void kernel_launch(void* const* d_in, const int* in_sizes, int n_in,
                              void* d_out, int out_size, void* d_ws, size_t ws_size,
                              hipStream_t stream) {
    const float* dh  = (const float*)d_in[0];  // [64,512]
    const float* enc = (const float*)d_in[1];  // [64,2048,512]
    const float* Wa  = (const float*)d_in[2];  // [512,128]
    const float* ba  = (const float*)d_in[3];  // [128]
    const float* Wb  = (const float*)d_in[4];  // [512,128]
    const float* bb  = (const float*)d_in[5];  // [128]
    const float* Wv  = (const float*)d_in[6];  // [128,1]
    // d_in[7] = bv — cancels in softmax, unused.

    float* out      = (float*)d_out;
    float* ctx      = out;                 // [64,512]  = 32768 floats
    float* attn_out = out + (B_ * ENC_);   // [64,2048] = 131072 floats

    float* ws      = (float*)d_ws;
    float* q       = ws;                        // 8192 floats
    float* scores  = ws + 8192;                 // 131072 floats
    float* part    = ws + 8192 + (B_ * T_);     // 8*64*512 = 262144 floats

    qproj_kernel<<<B_, U_, 0, stream>>>(dh, Wa, ba, bb, q);
    score_kernel<<<(B_ * T_) / MBLK, 256, 0, stream>>>(enc, Wb, q, Wv, scores);
    softmax_kernel<<<B_, 256, 0, stream>>>(scores, attn_out);
    context_partial_kernel<<<dim3(8, B_), 256, 0, stream>>>(enc, attn_out, part);
    context_reduce_kernel<<<(B_ * ENC_) / 256, 256, 0, stream>>>(part, ctx);
}

// Round 2
// 507.099 us; speedup vs baseline: 1.1396x; 1.1396x over previous
//
#include <hip/hip_runtime.h>
#include <math.h>

// Problem constants (fixed shapes from reference)
#define B_   64
#define T_   2048
#define ENC_ 512
#define U_   128

typedef __attribute__((ext_vector_type(8))) short short8;
typedef __attribute__((ext_vector_type(4))) float float4v;

// round-to-nearest-even fp32 -> bf16 (finite inputs only)
__device__ inline unsigned short bf16_rtn(float x) {
    unsigned u = __float_as_uint(x);
    unsigned r = u + 0x7FFFu + ((u >> 16) & 1u);
    return (unsigned short)(r >> 16);
}
__device__ inline float bf16_to_f32(unsigned short h) {
    return __uint_as_float(((unsigned)h) << 16);
}

// ---------------------------------------------------------------------------
// Kernel A: q'[b][u] = dh[b,:] @ Wa[:,u] + ba[u] + bb[u]
// (bb folded in; bv dropped — it cancels in softmax over T)
// ---------------------------------------------------------------------------
__global__ void qproj_kernel(const float* __restrict__ dh,
                             const float* __restrict__ Wa,
                             const float* __restrict__ ba,
                             const float* __restrict__ bb,
                             float* __restrict__ q) {
    const int b = blockIdx.x;      // 64
    const int u = threadIdx.x;     // 128
    const float* dhb = dh + b * ENC_;
    float acc = 0.f;
#pragma unroll 8
    for (int e = 0; e < ENC_; ++e)
        acc += dhb[e] * Wa[e * U_ + u];
    q[b * U_ + u] = acc + ba[u] + bb[u];
}

// ---------------------------------------------------------------------------
// Kernel W: pre-swizzle Wb into MFMA B-fragment order, split hi/lo bf16.
// B-frag (16x16x32): lane L holds B[k=(L>>4)*8+j][n=(L&15)], j=0..7.
// Storage: frag id f = c*8+gn (c = k-chunk of 32, gn = n-group of 16);
//          whi[(f*64 + L)*8 + j]
// ---------------------------------------------------------------------------
__global__ void wprep_kernel(const float* __restrict__ Wb,
                             unsigned short* __restrict__ whi,
                             unsigned short* __restrict__ wlo) {
    const int fid = blockIdx.x;       // 0..127  (c*8+gn)
    const int c   = fid >> 3;
    const int gn  = fid & 7;
    const int L   = threadIdx.x;      // 0..63
    const int n   = gn * 16 + (L & 15);
    const int k0  = c * 32 + (L >> 4) * 8;
    short8 hi, lo;
#pragma unroll
    for (int j = 0; j < 8; ++j) {
        const float x = Wb[(size_t)(k0 + j) * U_ + n];
        const unsigned short h = bf16_rtn(x);
        hi[j] = (short)h;
        lo[j] = (short)bf16_rtn(x - bf16_to_f32(h));
    }
    *(short8*)(whi + ((size_t)fid * 64 + L) * 8) = hi;
    *(short8*)(wlo + ((size_t)fid * 64 + L) * 8) = lo;
}

// ---------------------------------------------------------------------------
// Kernel B: fused score GEMM via split-bf16 MFMA.
//   scores[m] = sum_u tanh(q'[b,u] + enc[m,:]@Wb[:,u]) * Wv[u]
// Block: 64 rows (m) x 128 cols (full U), 256 threads = 4 waves,
// wave w owns m-rowgroup w (16 rows), all 8 n-groups.
// A staged in LDS in fragment order (conflict-free b128), double-buffered,
// one barrier per k-chunk. B-frags loaded from pre-swizzled L2-resident ws.
// ---------------------------------------------------------------------------
#define MBLK 64

__global__ __launch_bounds__(256)
void score_mfma_kernel(const float* __restrict__ enc,
                       const unsigned short* __restrict__ whi,
                       const unsigned short* __restrict__ wlo,
                       const float* __restrict__ q,
                       const float* __restrict__ Wv,
                       float* __restrict__ scores) {
    // frag-ordered A: slot ((g*4+qd)*16 + r15) holds 8 bf16 (16 B)
    __shared__ __align__(16) short Ahi[2][64 * 32];
    __shared__ __align__(16) short Alo[2][64 * 32];

    const int tid = threadIdx.x;
    const int w   = tid >> 6;       // wave 0..3
    const int L   = tid & 63;
    const int m0  = blockIdx.x * MBLK;
    const int b   = m0 >> 11;       // 2048 t per batch; blocks never straddle b

    // staging coords: thread handles row srow, k-quad sqd (8 consecutive k)
    const int srow  = tid >> 2;     // 0..63
    const int sqd   = tid & 3;      // 0..3
    const int sfrag = ((srow >> 4) * 4 + sqd) * 16 + (srow & 15);
    const float* encRow = enc + (size_t)(m0 + srow) * ENC_ + sqd * 8;

    float4v acc[8];
#pragma unroll
    for (int gn = 0; gn < 8; ++gn) acc[gn] = (float4v)0.f;

    // prologue: stage chunk 0
    {
        const float4 a0 = *(const float4*)(encRow);
        const float4 a1 = *(const float4*)(encRow + 4);
        const float xs[8] = {a0.x, a0.y, a0.z, a0.w, a1.x, a1.y, a1.z, a1.w};
        short8 h, l;
#pragma unroll
        for (int j = 0; j < 8; ++j) {
            const unsigned short hb = bf16_rtn(xs[j]);
            h[j] = (short)hb;
            l[j] = (short)bf16_rtn(xs[j] - bf16_to_f32(hb));
        }
        *(short8*)(&Ahi[0][sfrag * 8]) = h;
        *(short8*)(&Alo[0][sfrag * 8]) = l;
    }
    __syncthreads();

    for (int c = 0; c < 16; ++c) {
        const int cur = c & 1;
        // issue next chunk's global loads early (latency hidden under MFMA)
        float4 n0, n1;
        if (c < 15) {
            n0 = *(const float4*)(encRow + (c + 1) * 32);
            n1 = *(const float4*)(encRow + (c + 1) * 32 + 4);
        }
        // A frags for this wave (conflict-free: lane L reads base + L*16)
        const short8 ah = *(const short8*)(&Ahi[cur][(w * 64 + L) * 8]);
        const short8 al = *(const short8*)(&Alo[cur][(w * 64 + L) * 8]);
        // B frags straight from L2-resident swizzled buffer
        const unsigned short* bh_base = whi + ((size_t)(c * 8) * 64 + L) * 8;
        const unsigned short* bl_base = wlo + ((size_t)(c * 8) * 64 + L) * 8;
#pragma unroll
        for (int gn = 0; gn < 8; ++gn) {
            const short8 bh = *(const short8*)(bh_base + (size_t)gn * 64 * 8);
            const short8 bl = *(const short8*)(bl_base + (size_t)gn * 64 * 8);
            acc[gn] = __builtin_amdgcn_mfma_f32_16x16x32_bf16(ah, bh, acc[gn], 0, 0, 0);
            acc[gn] = __builtin_amdgcn_mfma_f32_16x16x32_bf16(ah, bl, acc[gn], 0, 0, 0);
            acc[gn] = __builtin_amdgcn_mfma_f32_16x16x32_bf16(al, bh, acc[gn], 0, 0, 0);
        }
        // stage next chunk into the other buffer
        if (c < 15) {
            const int nxt = cur ^ 1;
            const float xs[8] = {n0.x, n0.y, n0.z, n0.w, n1.x, n1.y, n1.z, n1.w};
            short8 h, l;
#pragma unroll
            for (int j = 0; j < 8; ++j) {
                const unsigned short hb = bf16_rtn(xs[j]);
                h[j] = (short)hb;
                l[j] = (short)bf16_rtn(xs[j] - bf16_to_f32(hb));
            }
            *(short8*)(&Ahi[nxt][sfrag * 8]) = h;
            *(short8*)(&Alo[nxt][sfrag * 8]) = l;
        }
        __syncthreads();
    }

    // ---- epilogue: tanh + Wv dot + cross-lane reduce over u ----
    // C/D layout (verified): col(u) = L&15 (+gn*16), row = (L>>4)*4 + reg
    const int n15 = L & 15;
    float qv[8], wvv[8];
#pragma unroll
    for (int gn = 0; gn < 8; ++gn) {
        qv[gn]  = q[b * U_ + gn * 16 + n15];
        wvv[gn] = Wv[gn * 16 + n15];
    }
    const int rbase = m0 + w * 16 + (L >> 4) * 4;
#pragma unroll
    for (int r = 0; r < 4; ++r) {
        float s = 0.f;
#pragma unroll
        for (int gn = 0; gn < 8; ++gn)
            s += tanhf(qv[gn] + acc[gn][r]) * wvv[gn];
        s += __shfl_xor(s, 1, 64);
        s += __shfl_xor(s, 2, 64);
        s += __shfl_xor(s, 4, 64);
        s += __shfl_xor(s, 8, 64);
        if (n15 == 0) scores[rbase + r] = s;
    }
}

// ---------------------------------------------------------------------------
// Kernel C: softmax over T per batch. One block per b, 256 threads x 8 vals.
// ---------------------------------------------------------------------------
__global__ void softmax_kernel(const float* __restrict__ scores,
                               float* __restrict__ attn) {
    const int b   = blockIdx.x;
    const int tid = threadIdx.x;
    const float* s = scores + b * T_;

    float v[8];
    float mx = -1e30f;
#pragma unroll
    for (int i = 0; i < 8; ++i) {
        v[i] = s[tid + i * 256];
        mx = fmaxf(mx, v[i]);
    }
    for (int off = 1; off < 64; off <<= 1)
        mx = fmaxf(mx, __shfl_xor(mx, off, 64));
    __shared__ float redm[4];
    __shared__ float reds[4];
    if ((tid & 63) == 0) redm[tid >> 6] = mx;
    __syncthreads();
    mx = fmaxf(fmaxf(redm[0], redm[1]), fmaxf(redm[2], redm[3]));

    float sum = 0.f;
#pragma unroll
    for (int i = 0; i < 8; ++i) {
        v[i] = expf(v[i] - mx);
        sum += v[i];
    }
    for (int off = 1; off < 64; off <<= 1)
        sum += __shfl_xor(sum, off, 64);
    if ((tid & 63) == 0) reds[tid >> 6] = sum;
    __syncthreads();
    sum = reds[0] + reds[1] + reds[2] + reds[3];
    const float inv = 1.f / sum;
#pragma unroll
    for (int i = 0; i < 8; ++i)
        attn[b * T_ + tid + i * 256] = v[i] * inv;
}

// ---------------------------------------------------------------------------
// Kernel Z: zero the context region of d_out (harness poisons it 0xAA).
// ---------------------------------------------------------------------------
__global__ void zero_ctx_kernel(float* __restrict__ ctx) {
    ctx[blockIdx.x * 256 + threadIdx.x] = 0.f;
}

// ---------------------------------------------------------------------------
// Kernel D: context via atomics. Grid (16 t-chunks x 64 b), 256 threads.
// Each block streams 128 t-rows (coalesced float2) and atomicAdds its
// 512-float partial into ctx.
// ---------------------------------------------------------------------------
__global__ __launch_bounds__(256)
void context_atomic_kernel(const float* __restrict__ enc,
                           const float* __restrict__ attn,
                           float* __restrict__ ctx) {
    const int ch  = blockIdx.x;   // 0..15
    const int b   = blockIdx.y;   // 0..63
    const int tid = threadIdx.x;  // 0..255

    __shared__ float aw[128];
    if (tid < 128) aw[tid] = attn[b * T_ + ch * 128 + tid];
    __syncthreads();

    const float* ebase = enc + ((size_t)b * T_ + ch * 128) * ENC_;
    float sx = 0.f, sy = 0.f;
#pragma unroll 4
    for (int t = 0; t < 128; ++t) {
        const float wgt = aw[t];
        const float2 v = *(const float2*)(ebase + (size_t)t * ENC_ + tid * 2);
        sx += wgt * v.x;
        sy += wgt * v.y;
    }
    atomicAdd(&ctx[b * ENC_ + tid * 2], sx);
    atomicAdd(&ctx[b * ENC_ + tid * 2 + 1], sy);
}

// ---------------------------------------------------------------------------
extern "C" void kernel_launch(void* const* d_in, const int* in_sizes, int n_in,
                              void* d_out, int out_size, void* d_ws, size_t ws_size,
                              hipStream_t stream) {
    const float* dh  = (const float*)d_in[0];  // [64,512]
    const float* enc = (const float*)d_in[1];  // [64,2048,512]
    const float* Wa  = (const float*)d_in[2];  // [512,128]
    const float* ba  = (const float*)d_in[3];  // [128]
    const float* Wb  = (const float*)d_in[4];  // [512,128]
    const float* bb  = (const float*)d_in[5];  // [128]
    const float* Wv  = (const float*)d_in[6];  // [128,1]
    // d_in[7] = bv — cancels in softmax, unused.

    float* out      = (float*)d_out;
    float* ctx      = out;                 // [64,512]
    float* attn_out = out + (B_ * ENC_);   // [64,2048]

    float* ws           = (float*)d_ws;
    float* q            = ws;                                  // 8192 f
    float* scores       = ws + 8192;                           // 131072 f
    unsigned short* whi = (unsigned short*)(ws + 8192 + B_ * T_); // 65536 u16
    unsigned short* wlo = whi + 16 * 8 * 64 * 8;                  // 65536 u16

    qproj_kernel<<<B_, U_, 0, stream>>>(dh, Wa, ba, bb, q);
    wprep_kernel<<<128, 64, 0, stream>>>(Wb, whi, wlo);
    score_mfma_kernel<<<(B_ * T_) / MBLK, 256, 0, stream>>>(enc, whi, wlo, q, Wv, scores);
    softmax_kernel<<<B_, 256, 0, stream>>>(scores, attn_out);
    zero_ctx_kernel<<<(B_ * ENC_) / 256, 256, 0, stream>>>(ctx);
    context_atomic_kernel<<<dim3(16, B_), 256, 0, stream>>>(enc, attn_out, ctx);
}

// Round 3
// 498.081 us; speedup vs baseline: 1.1602x; 1.0181x over previous
//
#include <hip/hip_runtime.h>
#include <math.h>

// Problem constants (fixed shapes from reference)
#define B_   64
#define T_   2048
#define ENC_ 512
#define U_   128
#define NC   16      // K chunks of 32

typedef __attribute__((ext_vector_type(8))) short short8;
typedef __attribute__((ext_vector_type(4))) float float4v;

// round-to-nearest-even fp32 -> bf16 (finite inputs only)
__device__ inline unsigned short bf16_rtn(float x) {
    unsigned u = __float_as_uint(x);
    unsigned r = u + 0x7FFFu + ((u >> 16) & 1u);
    return (unsigned short)(r >> 16);
}
__device__ inline float bf16_to_f32(unsigned short h) {
    return __uint_as_float(((unsigned)h) << 16);
}

// split x into hi (RNE bf16) + lo (truncated bf16 of remainder): err ~2^-17|x|
__device__ inline void cvt_split8(const float4 a0, const float4 a1,
                                  short8& h, short8& l) {
    const float xs[8] = {a0.x, a0.y, a0.z, a0.w, a1.x, a1.y, a1.z, a1.w};
#pragma unroll
    for (int j = 0; j < 8; ++j) {
        const unsigned u  = __float_as_uint(xs[j]);
        const unsigned r  = u + 0x7FFFu + ((u >> 16) & 1u);
        const unsigned hb = r >> 16;
        h[j] = (short)hb;
        const float d = xs[j] - __uint_as_float(hb << 16);
        l[j] = (short)(__float_as_uint(d) >> 16);
    }
}

// tanh via single v_exp: 1 - 2/(e^{2x}+1); exact at ±inf, err ~1e-6
__device__ inline float fast_tanh(float x) {
    const float e = __expf(2.0f * x);
    return 1.0f - 2.0f / (e + 1.0f);
}

// ---------------------------------------------------------------------------
// Kernel A: q'[b][u] = dh[b,:] @ Wa[:,u] + ba[u] + bb[u]
// (bb folded in; bv dropped — it cancels in softmax over T)
// ---------------------------------------------------------------------------
__global__ void qproj_kernel(const float* __restrict__ dh,
                             const float* __restrict__ Wa,
                             const float* __restrict__ ba,
                             const float* __restrict__ bb,
                             float* __restrict__ q) {
    const int b = blockIdx.x;      // 64
    const int u = threadIdx.x;     // 128
    const float* dhb = dh + b * ENC_;
    float a0 = 0.f, a1 = 0.f, a2 = 0.f, a3 = 0.f;
#pragma unroll 4
    for (int e = 0; e < ENC_; e += 4) {
        a0 += dhb[e + 0] * Wa[(e + 0) * U_ + u];
        a1 += dhb[e + 1] * Wa[(e + 1) * U_ + u];
        a2 += dhb[e + 2] * Wa[(e + 2) * U_ + u];
        a3 += dhb[e + 3] * Wa[(e + 3) * U_ + u];
    }
    q[b * U_ + u] = ((a0 + a1) + (a2 + a3)) + ba[u] + bb[u];
}

// ---------------------------------------------------------------------------
// Kernel W: pre-swizzle Wb into MFMA B-fragment order, split hi/lo bf16.
// B-frag (16x16x32): lane L holds B[k=(L>>4)*8+j][n=(L&15)], j=0..7.
// frag id f = c*8+gn; whi[(f*64 + L)*8 + j]
// ---------------------------------------------------------------------------
__global__ void wprep_kernel(const float* __restrict__ Wb,
                             unsigned short* __restrict__ whi,
                             unsigned short* __restrict__ wlo) {
    const int fid = blockIdx.x;       // 0..127  (c*8+gn)
    const int c   = fid >> 3;
    const int gn  = fid & 7;
    const int L   = threadIdx.x;      // 0..63
    const int n   = gn * 16 + (L & 15);
    const int k0  = c * 32 + (L >> 4) * 8;
    short8 hi, lo;
#pragma unroll
    for (int j = 0; j < 8; ++j) {
        const float x = Wb[(size_t)(k0 + j) * U_ + n];
        const unsigned short h = bf16_rtn(x);
        hi[j] = (short)h;
        lo[j] = (short)bf16_rtn(x - bf16_to_f32(h));
    }
    *(short8*)(whi + ((size_t)fid * 64 + L) * 8) = hi;
    *(short8*)(wlo + ((size_t)fid * 64 + L) * 8) = lo;
}

// ---------------------------------------------------------------------------
// Kernel Z: zero uctx (+Zsum, contiguous)
// ---------------------------------------------------------------------------
__global__ void zero_kernel(float* __restrict__ p, int n) {
    const int i = blockIdx.x * 256 + threadIdx.x;
    if (i < n) p[i] = 0.f;
}

// ---------------------------------------------------------------------------
// Kernel B: fused score GEMM + exp + unnormalized context.
// Block: 128 rows x 128 U, 4 waves; wave w owns m-tiles {2w, 2w+1}.
// Phase 1: split-bf16 MFMA GEMM, fast-tanh/Wv epilogue, e_t = exp(s_t)
//          (no max-sub: |s| <= ||Wv||_1 ~ 11, fp32-safe, math-identical).
// Phase 2: re-read block's 128 enc rows (L2-hot) for sum_t e_t * enc[t,:],
//          atomicAdd partials into uctx, Zsum.
// ---------------------------------------------------------------------------
#define MBLK 128

__global__ __launch_bounds__(256, 2)
void score_ctx_kernel(const float* __restrict__ enc,
                      const unsigned short* __restrict__ whi,
                      const unsigned short* __restrict__ wlo,
                      const float* __restrict__ q,
                      const float* __restrict__ Wv,
                      float* __restrict__ expw,
                      float* __restrict__ uctx,
                      float* __restrict__ Zsum) {
    // frag-ordered A: slot ((mt*4+kq)*16 + r15) holds 8 bf16 (16 B)
    __shared__ __align__(16) short Ahi[2][4096];   // 8 KB each buffer
    __shared__ __align__(16) short Alo[2][4096];
    __shared__ float ew[MBLK];

    const int tid = threadIdx.x;
    const int w   = tid >> 6;       // wave 0..3
    const int L   = tid & 63;
    const int m0  = blockIdx.x * MBLK;
    const int b   = m0 >> 11;       // blocks never straddle a batch

    // staging: thread handles rows srow and srow+64, k-quad sqd (8 k each)
    const int srow = tid >> 2;      // 0..63
    const int sqd  = tid & 3;
    const int sf0  = ((srow >> 4) * 4 + sqd) * 16 + (srow & 15);
    const int sf1  = (((srow >> 4) + 4) * 4 + sqd) * 16 + (srow & 15);
    const float* encR0 = enc + (size_t)(m0 + srow) * ENC_ + sqd * 8;
    const float* encR1 = encR0 + (size_t)64 * ENC_;

    float4v acc0[8], acc1[8];
#pragma unroll
    for (int gn = 0; gn < 8; ++gn) { acc0[gn] = (float4v)0.f; acc1[gn] = (float4v)0.f; }

    // prologue: stage chunk 0
    {
        short8 h, l;
        cvt_split8(*(const float4*)(encR0), *(const float4*)(encR0 + 4), h, l);
        *(short8*)(&Ahi[0][sf0 * 8]) = h;
        *(short8*)(&Alo[0][sf0 * 8]) = l;
        cvt_split8(*(const float4*)(encR1), *(const float4*)(encR1 + 4), h, l);
        *(short8*)(&Ahi[0][sf1 * 8]) = h;
        *(short8*)(&Alo[0][sf1 * 8]) = l;
    }
    __syncthreads();

    for (int c = 0; c < NC; ++c) {
        const int cur = c & 1;
        // prefetch next chunk's A rows (global, hidden under MFMA)
        float4 p00, p01, p10, p11;
        if (c < NC - 1) {
            p00 = *(const float4*)(encR0 + (c + 1) * 32);
            p01 = *(const float4*)(encR0 + (c + 1) * 32 + 4);
            p10 = *(const float4*)(encR1 + (c + 1) * 32);
            p11 = *(const float4*)(encR1 + (c + 1) * 32 + 4);
        }
        // A frags for this wave's two m-tiles (lane L reads base + L*16)
        const short8 ah0 = *(const short8*)(&Ahi[cur][((2 * w + 0) * 64 + L) * 8]);
        const short8 al0 = *(const short8*)(&Alo[cur][((2 * w + 0) * 64 + L) * 8]);
        const short8 ah1 = *(const short8*)(&Ahi[cur][((2 * w + 1) * 64 + L) * 8]);
        const short8 al1 = *(const short8*)(&Alo[cur][((2 * w + 1) * 64 + L) * 8]);
        const unsigned short* bh_base = whi + ((size_t)(c * 8) * 64 + L) * 8;
        const unsigned short* bl_base = wlo + ((size_t)(c * 8) * 64 + L) * 8;
#pragma unroll
        for (int gn = 0; gn < 8; ++gn) {
            const short8 bh = *(const short8*)(bh_base + (size_t)gn * 512);
            const short8 bl = *(const short8*)(bl_base + (size_t)gn * 512);
            acc0[gn] = __builtin_amdgcn_mfma_f32_16x16x32_bf16(ah0, bh, acc0[gn], 0, 0, 0);
            acc0[gn] = __builtin_amdgcn_mfma_f32_16x16x32_bf16(ah0, bl, acc0[gn], 0, 0, 0);
            acc0[gn] = __builtin_amdgcn_mfma_f32_16x16x32_bf16(al0, bh, acc0[gn], 0, 0, 0);
            acc1[gn] = __builtin_amdgcn_mfma_f32_16x16x32_bf16(ah1, bh, acc1[gn], 0, 0, 0);
            acc1[gn] = __builtin_amdgcn_mfma_f32_16x16x32_bf16(ah1, bl, acc1[gn], 0, 0, 0);
            acc1[gn] = __builtin_amdgcn_mfma_f32_16x16x32_bf16(al1, bh, acc1[gn], 0, 0, 0);
        }
        // stage next chunk into the other buffer
        if (c < NC - 1) {
            const int nxt = cur ^ 1;
            short8 h, l;
            cvt_split8(p00, p01, h, l);
            *(short8*)(&Ahi[nxt][sf0 * 8]) = h;
            *(short8*)(&Alo[nxt][sf0 * 8]) = l;
            cvt_split8(p10, p11, h, l);
            *(short8*)(&Ahi[nxt][sf1 * 8]) = h;
            *(short8*)(&Alo[nxt][sf1 * 8]) = l;
        }
        __syncthreads();
    }

    // ---- epilogue: tanh + Wv dot + reduce over u; e = exp(score) ----
    // C/D layout: col(u) = L&15 (+gn*16), row = (L>>4)*4 + reg
    const int n15 = L & 15;
    float qv[8], wvv[8];
#pragma unroll
    for (int gn = 0; gn < 8; ++gn) {
        qv[gn]  = q[b * U_ + gn * 16 + n15];
        wvv[gn] = Wv[gn * 16 + n15];
    }
#pragma unroll
    for (int tt = 0; tt < 2; ++tt) {
        const float4v* accp = tt ? acc1 : acc0;
#pragma unroll
        for (int r = 0; r < 4; ++r) {
            float s = 0.f;
#pragma unroll
            for (int gn = 0; gn < 8; ++gn)
                s += fast_tanh(qv[gn] + accp[gn][r]) * wvv[gn];
            s += __shfl_xor(s, 1, 64);
            s += __shfl_xor(s, 2, 64);
            s += __shfl_xor(s, 4, 64);
            s += __shfl_xor(s, 8, 64);
            if (n15 == 0) {
                const int rloc = (2 * w + tt) * 16 + (L >> 4) * 4 + r;
                const float e = __expf(s);
                ew[rloc] = e;
                expw[m0 + rloc] = e;
            }
        }
    }
    __syncthreads();

    // ---- phase 2: unnormalized context over this block's 128 rows ----
    const int col = tid * 2;
    const float* ebase = enc + (size_t)m0 * ENC_ + col;
    float sx = 0.f, sy = 0.f;
#pragma unroll 8
    for (int t = 0; t < MBLK; ++t) {
        const float wgt = ew[t];                       // LDS broadcast
        const float2 v = *(const float2*)(ebase + (size_t)t * ENC_);
        sx += wgt * v.x;
        sy += wgt * v.y;
    }
    atomicAdd(&uctx[b * ENC_ + col], sx);
    atomicAdd(&uctx[b * ENC_ + col + 1], sy);

    if (tid < 64) {
        float z = ew[tid] + ew[tid + 64];
        z += __shfl_xor(z, 1, 64);
        z += __shfl_xor(z, 2, 64);
        z += __shfl_xor(z, 4, 64);
        z += __shfl_xor(z, 8, 64);
        z += __shfl_xor(z, 16, 64);
        z += __shfl_xor(z, 32, 64);
        if (tid == 0) atomicAdd(&Zsum[b], z);
    }
}

// ---------------------------------------------------------------------------
// Kernel N: normalize — ctx = uctx/Z, attn = expw/Z. 640 blocks x 256.
// ---------------------------------------------------------------------------
__global__ void normalize_kernel(const float* __restrict__ uctx,
                                 const float* __restrict__ Zsum,
                                 const float* __restrict__ expw,
                                 float* __restrict__ ctx,
                                 float* __restrict__ attn) {
    const int idx = blockIdx.x * 256 + threadIdx.x;
    if (idx < B_ * ENC_) {
        ctx[idx] = uctx[idx] / Zsum[idx >> 9];        // ENC_ = 512
    } else {
        const int i2 = idx - B_ * ENC_;
        attn[i2] = expw[i2] / Zsum[i2 >> 11];         // T_ = 2048
    }
}

// ---------------------------------------------------------------------------
extern "C" void kernel_launch(void* const* d_in, const int* in_sizes, int n_in,
                              void* d_out, int out_size, void* d_ws, size_t ws_size,
                              hipStream_t stream) {
    const float* dh  = (const float*)d_in[0];  // [64,512]
    const float* enc = (const float*)d_in[1];  // [64,2048,512]
    const float* Wa  = (const float*)d_in[2];  // [512,128]
    const float* ba  = (const float*)d_in[3];  // [128]
    const float* Wb  = (const float*)d_in[4];  // [512,128]
    const float* bb  = (const float*)d_in[5];  // [128]
    const float* Wv  = (const float*)d_in[6];  // [128,1]
    // d_in[7] = bv — cancels in softmax, unused.

    float* out      = (float*)d_out;
    float* ctx      = out;                 // [64,512]
    float* attn_out = out + (B_ * ENC_);   // [64,2048]

    float* ws   = (float*)d_ws;
    float* q    = ws;                              // 8192
    float* expw = ws + 8192;                       // 131072
    float* uctx = ws + 8192 + B_ * T_;             // 32768
    float* Zs   = uctx + B_ * ENC_;                // 64 (contiguous after uctx)
    unsigned short* whi = (unsigned short*)(Zs + 64);   // 65536 u16
    unsigned short* wlo = whi + 65536;                  // 65536 u16

    qproj_kernel<<<B_, U_, 0, stream>>>(dh, Wa, ba, bb, q);
    wprep_kernel<<<128, 64, 0, stream>>>(Wb, whi, wlo);
    zero_kernel<<<129, 256, 0, stream>>>(uctx, B_ * ENC_ + B_);
    score_ctx_kernel<<<(B_ * T_) / MBLK, 256, 0, stream>>>(enc, whi, wlo, q, Wv,
                                                           expw, uctx, Zs);
    normalize_kernel<<<(B_ * (ENC_ + T_)) / 256, 256, 0, stream>>>(uctx, Zs, expw,
                                                                   ctx, attn_out);
}

// Round 4
// 433.570 us; speedup vs baseline: 1.3328x; 1.1488x over previous
//
#include <hip/hip_runtime.h>
#include <math.h>

// Problem constants (fixed shapes from reference)
#define B_   64
#define T_   2048
#define ENC_ 512
#define U_   128
#define NC   16      // K chunks of 32
#define MBLK 128

typedef __attribute__((ext_vector_type(8))) short short8;
typedef __attribute__((ext_vector_type(4))) float float4v;

// round-to-nearest-even fp32 -> bf16 (finite inputs only)
__device__ inline unsigned short bf16_rtn(float x) {
    unsigned u = __float_as_uint(x);
    unsigned r = u + 0x7FFFu + ((u >> 16) & 1u);
    return (unsigned short)(r >> 16);
}
__device__ inline float bf16_to_f32(unsigned short h) {
    return __uint_as_float(((unsigned)h) << 16);
}

// split x into hi (RNE bf16) + lo (truncated bf16 of remainder): err ~2^-17|x|
__device__ inline void cvt_split8(const float4 a0, const float4 a1,
                                  short8& h, short8& l) {
    const float xs[8] = {a0.x, a0.y, a0.z, a0.w, a1.x, a1.y, a1.z, a1.w};
#pragma unroll
    for (int j = 0; j < 8; ++j) {
        const unsigned u  = __float_as_uint(xs[j]);
        const unsigned r  = u + 0x7FFFu + ((u >> 16) & 1u);
        const unsigned hb = r >> 16;
        h[j] = (short)hb;
        const float d = xs[j] - __uint_as_float(hb << 16);
        l[j] = (short)(__float_as_uint(d) >> 16);
    }
}

// tanh via single v_exp: 1 - 2/(e^{2x}+1); exact at ±inf, err ~1e-6
__device__ inline float fast_tanh(float x) {
    const float e = __expf(2.0f * x);
    return 1.0f - 2.0f / (e + 1.0f);
}

// ---------------------------------------------------------------------------
// Kernel A: q'[b][u] = dh[b,:] @ Wa[:,u] + ba[u] + bb[u]
// ---------------------------------------------------------------------------
__global__ void qproj_kernel(const float* __restrict__ dh,
                             const float* __restrict__ Wa,
                             const float* __restrict__ ba,
                             const float* __restrict__ bb,
                             float* __restrict__ q) {
    const int b = blockIdx.x;      // 64
    const int u = threadIdx.x;     // 128
    const float* dhb = dh + b * ENC_;
    float a0 = 0.f, a1 = 0.f, a2 = 0.f, a3 = 0.f;
#pragma unroll 4
    for (int e = 0; e < ENC_; e += 4) {
        a0 += dhb[e + 0] * Wa[(e + 0) * U_ + u];
        a1 += dhb[e + 1] * Wa[(e + 1) * U_ + u];
        a2 += dhb[e + 2] * Wa[(e + 2) * U_ + u];
        a3 += dhb[e + 3] * Wa[(e + 3) * U_ + u];
    }
    q[b * U_ + u] = ((a0 + a1) + (a2 + a3)) + ba[u] + bb[u];
}

// ---------------------------------------------------------------------------
// Kernel W: pre-swizzle Wb into MFMA B-fragment order, split hi/lo bf16.
// B-frag (16x16x32): lane L holds B[k=(L>>4)*8+j][n=(L&15)], j=0..7.
// frag id f = c*8+gn; whi[(f*64 + L)*8 + j] — chunk c is a contiguous
// 4096-short (8 KB) block, staged linearly into LDS by the score kernel.
// ---------------------------------------------------------------------------
__global__ void wprep_kernel(const float* __restrict__ Wb,
                             unsigned short* __restrict__ whi,
                             unsigned short* __restrict__ wlo) {
    const int fid = blockIdx.x;       // 0..127  (c*8+gn)
    const int c   = fid >> 3;
    const int gn  = fid & 7;
    const int L   = threadIdx.x;      // 0..63
    const int n   = gn * 16 + (L & 15);
    const int k0  = c * 32 + (L >> 4) * 8;
    short8 hi, lo;
#pragma unroll
    for (int j = 0; j < 8; ++j) {
        const float x = Wb[(size_t)(k0 + j) * U_ + n];
        const unsigned short h = bf16_rtn(x);
        hi[j] = (short)h;
        lo[j] = (short)bf16_rtn(x - bf16_to_f32(h));
    }
    *(short8*)(whi + ((size_t)fid * 64 + L) * 8) = hi;
    *(short8*)(wlo + ((size_t)fid * 64 + L) * 8) = lo;
}

// ---------------------------------------------------------------------------
// Kernel Z: zero uctx (+Zsum, contiguous)
// ---------------------------------------------------------------------------
__global__ void zero_kernel(float* __restrict__ p, int n) {
    const int i = blockIdx.x * 256 + threadIdx.x;
    if (i < n) p[i] = 0.f;
}

// ---------------------------------------------------------------------------
// Kernel B: fused score GEMM + exp + unnormalized context.
// 128 rows x 128 U per block, 4 waves in a 2x2 grid: wave (wr,wc) computes
// a 64x64 output tile -> 48 MFMAs per 16 LDS frag-reads per chunk
// (m97-balanced). A and B both staged through double-buffered LDS with
// register prefetch issued at chunk top (full MFMA loop of latency slack).
// Epilogue: per-wave tanh*Wv partial over its 64 u, cross-wave pair
// reduction in LDS, e = exp(score) (no max-sub: |s| <= ||Wv||_1, safe).
// Phase 2: block's 128 enc rows (L2-hot) -> atomicAdd unnormalized context.
// ---------------------------------------------------------------------------
__global__ __launch_bounds__(256)
void score_ctx_kernel(const float* __restrict__ enc,
                      const unsigned short* __restrict__ whi,
                      const unsigned short* __restrict__ wlo,
                      const float* __restrict__ q,
                      const float* __restrict__ Wv,
                      float* __restrict__ expw,
                      float* __restrict__ uctx,
                      float* __restrict__ Zsum) {
    // A frag order: slot ((mt*4+kq)*16 + r) -> lane-linear reads (mt*64+L)
    __shared__ __align__(16) short Ahi[2][4096];   // 8 KB per buffer
    __shared__ __align__(16) short Alo[2][4096];
    __shared__ __align__(16) short Bhi[2][4096];   // slot (gn*64+L)
    __shared__ __align__(16) short Blo[2][4096];
    __shared__ float sred[2 * MBLK];               // cross-wave partials
    __shared__ float ew[MBLK];

    const int tid = threadIdx.x;
    const int w   = tid >> 6;       // wave 0..3
    const int L   = tid & 63;
    const int wr  = w >> 1;         // m half (64 rows)
    const int wc  = w & 1;          // u half (64 cols)
    const int m0  = blockIdx.x * MBLK;
    const int b   = m0 >> 11;       // blocks never straddle a batch

    // A staging coords: rows srow, srow+64; k-quad sqd (8 k each)
    const int srow = tid >> 2;      // 0..63
    const int sqd  = tid & 3;
    const int sf0  = ((srow >> 4) * 4 + sqd) * 16 + (srow & 15);
    const int sf1  = sf0 + 256;
    const float* encR0 = enc + (size_t)(m0 + srow) * ENC_ + sqd * 8;
    const float* encR1 = encR0 + (size_t)64 * ENC_;

    float4v acc[4][4];
#pragma unroll
    for (int mi = 0; mi < 4; ++mi)
#pragma unroll
        for (int gi = 0; gi < 4; ++gi) acc[mi][gi] = (float4v)0.f;

    // ---- prologue: stage chunk 0 ----
    {
        short8 h, l;
        cvt_split8(*(const float4*)(encR0), *(const float4*)(encR0 + 4), h, l);
        *(short8*)(&Ahi[0][sf0 * 8]) = h;
        *(short8*)(&Alo[0][sf0 * 8]) = l;
        cvt_split8(*(const float4*)(encR1), *(const float4*)(encR1 + 4), h, l);
        *(short8*)(&Ahi[0][sf1 * 8]) = h;
        *(short8*)(&Alo[0][sf1 * 8]) = l;
        // B chunk 0: 4096 shorts hi + 4096 lo, thread copies 16 shorts each
        *(short8*)(&Bhi[0][tid * 16])     = *(const short8*)(whi + tid * 16);
        *(short8*)(&Bhi[0][tid * 16 + 8]) = *(const short8*)(whi + tid * 16 + 8);
        *(short8*)(&Blo[0][tid * 16])     = *(const short8*)(wlo + tid * 16);
        *(short8*)(&Blo[0][tid * 16 + 8]) = *(const short8*)(wlo + tid * 16 + 8);
    }
    __syncthreads();

    for (int c = 0; c < NC; ++c) {
        const int cur = c & 1;
        // ---- register prefetch for chunk c+1 (consumed after MFMA loop) ----
        float4 pa0, pa1, pa2, pa3;
        short8 pbh0, pbh1, pbl0, pbl1;
        if (c < NC - 1) {
            pa0 = *(const float4*)(encR0 + (c + 1) * 32);
            pa1 = *(const float4*)(encR0 + (c + 1) * 32 + 4);
            pa2 = *(const float4*)(encR1 + (c + 1) * 32);
            pa3 = *(const float4*)(encR1 + (c + 1) * 32 + 4);
            const unsigned short* bh = whi + (size_t)(c + 1) * 4096 + tid * 16;
            const unsigned short* bl = wlo + (size_t)(c + 1) * 4096 + tid * 16;
            pbh0 = *(const short8*)(bh);
            pbh1 = *(const short8*)(bh + 8);
            pbl0 = *(const short8*)(bl);
            pbl1 = *(const short8*)(bl + 8);
        }

        // ---- LDS frag reads (lane-linear, 16 B/lane) ----
        short8 ah[4], al[4], bh[4], bl[4];
#pragma unroll
        for (int mi = 0; mi < 4; ++mi) {
            const int mt = wr * 4 + mi;
            ah[mi] = *(const short8*)(&Ahi[cur][(mt * 64 + L) * 8]);
            al[mi] = *(const short8*)(&Alo[cur][(mt * 64 + L) * 8]);
        }
#pragma unroll
        for (int gi = 0; gi < 4; ++gi) {
            const int gt = wc * 4 + gi;
            bh[gi] = *(const short8*)(&Bhi[cur][(gt * 64 + L) * 8]);
            bl[gi] = *(const short8*)(&Blo[cur][(gt * 64 + L) * 8]);
        }

        // ---- 48 MFMAs ----
#pragma unroll
        for (int mi = 0; mi < 4; ++mi)
#pragma unroll
            for (int gi = 0; gi < 4; ++gi) {
                acc[mi][gi] = __builtin_amdgcn_mfma_f32_16x16x32_bf16(ah[mi], bh[gi], acc[mi][gi], 0, 0, 0);
                acc[mi][gi] = __builtin_amdgcn_mfma_f32_16x16x32_bf16(ah[mi], bl[gi], acc[mi][gi], 0, 0, 0);
                acc[mi][gi] = __builtin_amdgcn_mfma_f32_16x16x32_bf16(al[mi], bh[gi], acc[mi][gi], 0, 0, 0);
            }

        // ---- write prefetched chunk c+1 into the other buffer ----
        if (c < NC - 1) {
            const int nxt = cur ^ 1;
            short8 h, l;
            cvt_split8(pa0, pa1, h, l);
            *(short8*)(&Ahi[nxt][sf0 * 8]) = h;
            *(short8*)(&Alo[nxt][sf0 * 8]) = l;
            cvt_split8(pa2, pa3, h, l);
            *(short8*)(&Ahi[nxt][sf1 * 8]) = h;
            *(short8*)(&Alo[nxt][sf1 * 8]) = l;
            *(short8*)(&Bhi[nxt][tid * 16])     = pbh0;
            *(short8*)(&Bhi[nxt][tid * 16 + 8]) = pbh1;
            *(short8*)(&Blo[nxt][tid * 16])     = pbl0;
            *(short8*)(&Blo[nxt][tid * 16 + 8]) = pbl1;
        }
        __syncthreads();
    }

    // ---- epilogue: tanh + Wv partial dot over this wave's 64 u ----
    // C/D layout: col(u) = L&15 (+gt*16), row = (L>>4)*4 + reg
    const int n15 = L & 15;
    float qv[4], wvv[4];
#pragma unroll
    for (int gi = 0; gi < 4; ++gi) {
        const int u = wc * 64 + gi * 16 + n15;
        qv[gi]  = q[b * U_ + u];
        wvv[gi] = Wv[u];
    }
#pragma unroll
    for (int mi = 0; mi < 4; ++mi) {
#pragma unroll
        for (int r = 0; r < 4; ++r) {
            float s = 0.f;
#pragma unroll
            for (int gi = 0; gi < 4; ++gi)
                s += fast_tanh(qv[gi] + acc[mi][gi][r]) * wvv[gi];
            s += __shfl_xor(s, 1, 64);
            s += __shfl_xor(s, 2, 64);
            s += __shfl_xor(s, 4, 64);
            s += __shfl_xor(s, 8, 64);
            if (n15 == 0) {
                const int mrow = wr * 64 + mi * 16 + (L >> 4) * 4 + r;
                sred[wc * MBLK + mrow] = s;
            }
        }
    }
    __syncthreads();

    // combine wave-pair partials, exp, store
    if (tid < MBLK) {
        const float s = sred[tid] + sred[MBLK + tid];
        const float e = __expf(s);
        ew[tid] = e;
        expw[m0 + tid] = e;
    }
    __syncthreads();

    // ---- phase 2: unnormalized context over this block's 128 rows ----
    const int col = tid * 2;
    const float* ebase = enc + (size_t)m0 * ENC_ + col;
    float sx = 0.f, sy = 0.f;
#pragma unroll 8
    for (int t = 0; t < MBLK; ++t) {
        const float wgt = ew[t];                       // LDS broadcast
        const float2 v = *(const float2*)(ebase + (size_t)t * ENC_);
        sx += wgt * v.x;
        sy += wgt * v.y;
    }
    atomicAdd(&uctx[b * ENC_ + col], sx);
    atomicAdd(&uctx[b * ENC_ + col + 1], sy);

    if (tid < 64) {
        float z = ew[tid] + ew[tid + 64];
        z += __shfl_xor(z, 1, 64);
        z += __shfl_xor(z, 2, 64);
        z += __shfl_xor(z, 4, 64);
        z += __shfl_xor(z, 8, 64);
        z += __shfl_xor(z, 16, 64);
        z += __shfl_xor(z, 32, 64);
        if (tid == 0) atomicAdd(&Zsum[b], z);
    }
}

// ---------------------------------------------------------------------------
// Kernel N: normalize — ctx = uctx/Z, attn = expw/Z.
// ---------------------------------------------------------------------------
__global__ void normalize_kernel(const float* __restrict__ uctx,
                                 const float* __restrict__ Zsum,
                                 const float* __restrict__ expw,
                                 float* __restrict__ ctx,
                                 float* __restrict__ attn) {
    const int idx = blockIdx.x * 256 + threadIdx.x;
    if (idx < B_ * ENC_) {
        ctx[idx] = uctx[idx] / Zsum[idx >> 9];        // ENC_ = 512
    } else {
        const int i2 = idx - B_ * ENC_;
        attn[i2] = expw[i2] / Zsum[i2 >> 11];         // T_ = 2048
    }
}

// ---------------------------------------------------------------------------
extern "C" void kernel_launch(void* const* d_in, const int* in_sizes, int n_in,
                              void* d_out, int out_size, void* d_ws, size_t ws_size,
                              hipStream_t stream) {
    const float* dh  = (const float*)d_in[0];  // [64,512]
    const float* enc = (const float*)d_in[1];  // [64,2048,512]
    const float* Wa  = (const float*)d_in[2];  // [512,128]
    const float* ba  = (const float*)d_in[3];  // [128]
    const float* Wb  = (const float*)d_in[4];  // [512,128]
    const float* bb  = (const float*)d_in[5];  // [128]
    const float* Wv  = (const float*)d_in[6];  // [128,1]
    // d_in[7] = bv — cancels in softmax, unused.

    float* out      = (float*)d_out;
    float* ctx      = out;                 // [64,512]
    float* attn_out = out + (B_ * ENC_);   // [64,2048]

    float* ws   = (float*)d_ws;
    float* q    = ws;                              // 8192
    float* expw = ws + 8192;                       // 131072
    float* uctx = ws + 8192 + B_ * T_;             // 32768
    float* Zs   = uctx + B_ * ENC_;                // 64
    unsigned short* whi = (unsigned short*)(Zs + 64);   // 65536 u16
    unsigned short* wlo = whi + 65536;                  // 65536 u16

    qproj_kernel<<<B_, U_, 0, stream>>>(dh, Wa, ba, bb, q);
    wprep_kernel<<<128, 64, 0, stream>>>(Wb, whi, wlo);
    zero_kernel<<<129, 256, 0, stream>>>(uctx, B_ * ENC_ + B_);
    score_ctx_kernel<<<(B_ * T_) / MBLK, 256, 0, stream>>>(enc, whi, wlo, q, Wv,
                                                           expw, uctx, Zs);
    normalize_kernel<<<(B_ * (ENC_ + T_)) / 256, 256, 0, stream>>>(uctx, Zs, expw,
                                                                   ctx, attn_out);
}

// Round 5
// 432.171 us; speedup vs baseline: 1.3372x; 1.0032x over previous
//
#include <hip/hip_runtime.h>
#include <math.h>

// Problem constants (fixed shapes from reference)
#define B_   64
#define T_   2048
#define ENC_ 512
#define U_   128
#define NC   16      // K chunks of 32
#define MBLK 128

typedef __attribute__((ext_vector_type(8))) _Float16 half8;
typedef __attribute__((ext_vector_type(4))) float float4v;

// split x into hi (RTN fp16) + lo (fp16 of remainder): combined err ~2^-22|x|
__device__ inline void cvt_split8_f16(const float4 a0, const float4 a1,
                                      half8& h, half8& l) {
    const float xs[8] = {a0.x, a0.y, a0.z, a0.w, a1.x, a1.y, a1.z, a1.w};
#pragma unroll
    for (int j = 0; j < 8; ++j) {
        const _Float16 hi = (_Float16)xs[j];
        h[j] = hi;
        l[j] = (_Float16)(xs[j] - (float)hi);
    }
}

// tanh via single v_exp: 1 - 2/(e^{2x}+1); exact at ±inf, err ~1e-6
__device__ inline float fast_tanh(float x) {
    const float e = __expf(2.0f * x);
    return 1.0f - 2.0f / (e + 1.0f);
}

// ---------------------------------------------------------------------------
// Prep kernel (merged): blocks 0..63 qproj; 64..95 wprep; 96..224 zero.
//  qproj: q'[b][u] = dh[b,:]@Wa[:,u] + ba[u] + bb[u]  (bb folded; bv cancels)
//  wprep: Wb -> MFMA B-frag order, single fp16 (RTN).
//         B-frag (16x16x32): lane L holds B[k=(L>>4)*8+j][n=(L&15)].
//         frag f = c*8+gn; whf[(f*64+L)*8+j]; chunk c = contiguous 8 KB.
//  zero:  uctx (32768) + Zsum (64)
// ---------------------------------------------------------------------------
__global__ __launch_bounds__(256)
void prep_kernel(const float* __restrict__ dh,
                 const float* __restrict__ Wa,
                 const float* __restrict__ ba,
                 const float* __restrict__ bb,
                 const float* __restrict__ Wb,
                 float* __restrict__ q,
                 _Float16* __restrict__ whf,
                 float* __restrict__ uz) {
    const int blk = blockIdx.x;
    const int tid = threadIdx.x;
    if (blk < 64) {
        if (tid < U_) {
            const int b = blk, u = tid;
            const float* dhb = dh + b * ENC_;
            float a0 = 0.f, a1 = 0.f, a2 = 0.f, a3 = 0.f;
#pragma unroll 4
            for (int e = 0; e < ENC_; e += 4) {
                a0 += dhb[e + 0] * Wa[(e + 0) * U_ + u];
                a1 += dhb[e + 1] * Wa[(e + 1) * U_ + u];
                a2 += dhb[e + 2] * Wa[(e + 2) * U_ + u];
                a3 += dhb[e + 3] * Wa[(e + 3) * U_ + u];
            }
            q[b * U_ + u] = ((a0 + a1) + (a2 + a3)) + ba[u] + bb[u];
        }
    } else if (blk < 96) {
        const int fid = (blk - 64) * 4 + (tid >> 6);   // 0..127
        const int c   = fid >> 3;
        const int gn  = fid & 7;
        const int L   = tid & 63;
        const int n   = gn * 16 + (L & 15);
        const int k0  = c * 32 + (L >> 4) * 8;
        half8 hi;
#pragma unroll
        for (int j = 0; j < 8; ++j)
            hi[j] = (_Float16)Wb[(size_t)(k0 + j) * U_ + n];
        *(half8*)(whf + ((size_t)fid * 64 + L) * 8) = hi;
    } else {
        const int i = (blk - 96) * 256 + tid;
        if (i < B_ * ENC_ + B_) uz[i] = 0.f;
    }
}

// ---------------------------------------------------------------------------
// Kernel B: fused score GEMM + exp + unnormalized context.
// 128 rows x 128 U per block, 4 waves in 2x2 grid; wave tile 64x64.
// Split-fp16 A (hi+lo) x single-fp16 B -> 2 MFMAs/tile = 32 MFMAs per
// chunk per wave vs 12 LDS b128 frag reads. A and B double-buffered in
// LDS with register prefetch issued at chunk top. 49.5 KB LDS + <=170
// VGPR -> 3 blocks/CU.
// Epilogue: tanh*Wv partial per wave, cross-wave LDS reduce, e=exp(s)
// (no max-sub: |s| <= ||Wv||_1 ~ 11, fp32-safe, math-identical).
// Phase 2: block's 128 enc rows (L2/L3-hot) -> atomicAdd unnorm context.
// ---------------------------------------------------------------------------
__global__ __launch_bounds__(256, 3)
void score_ctx_kernel(const float* __restrict__ enc,
                      const _Float16* __restrict__ whf,
                      const float* __restrict__ q,
                      const float* __restrict__ Wv,
                      float* __restrict__ expw,
                      float* __restrict__ uctx,
                      float* __restrict__ Zsum) {
    // A frag order: slot ((mt*4+kq)*16 + r) -> lane-linear reads (mt*64+L)
    __shared__ __align__(16) _Float16 Ahi[2][4096];   // 8 KB per buffer
    __shared__ __align__(16) _Float16 Alo[2][4096];
    __shared__ __align__(16) _Float16 Bh[2][4096];    // slot (gn*64+L)
    __shared__ float sred[2 * MBLK];
    __shared__ float ew[MBLK];

    const int tid = threadIdx.x;
    const int w   = tid >> 6;       // wave 0..3
    const int L   = tid & 63;
    const int wr  = w >> 1;         // m half (64 rows)
    const int wc  = w & 1;          // u half (64 cols)
    const int m0  = blockIdx.x * MBLK;
    const int b   = m0 >> 11;       // blocks never straddle a batch

    // A staging coords: rows srow, srow+64; k-quad sqd (8 k each)
    const int srow = tid >> 2;      // 0..63
    const int sqd  = tid & 3;
    const int sf0  = ((srow >> 4) * 4 + sqd) * 16 + (srow & 15);
    const int sf1  = sf0 + 256;
    const float* encR0 = enc + (size_t)(m0 + srow) * ENC_ + sqd * 8;
    const float* encR1 = encR0 + (size_t)64 * ENC_;

    float4v acc[4][4];
#pragma unroll
    for (int mi = 0; mi < 4; ++mi)
#pragma unroll
        for (int gi = 0; gi < 4; ++gi) acc[mi][gi] = (float4v)0.f;

    // ---- prologue: stage chunk 0 ----
    {
        half8 h, l;
        cvt_split8_f16(*(const float4*)(encR0), *(const float4*)(encR0 + 4), h, l);
        *(half8*)(&Ahi[0][sf0 * 8]) = h;
        *(half8*)(&Alo[0][sf0 * 8]) = l;
        cvt_split8_f16(*(const float4*)(encR1), *(const float4*)(encR1 + 4), h, l);
        *(half8*)(&Ahi[0][sf1 * 8]) = h;
        *(half8*)(&Alo[0][sf1 * 8]) = l;
        // B chunk 0: 4096 halfs, thread copies 16 halfs (32 B)
        *(half8*)(&Bh[0][tid * 16])     = *(const half8*)(whf + tid * 16);
        *(half8*)(&Bh[0][tid * 16 + 8]) = *(const half8*)(whf + tid * 16 + 8);
    }
    __syncthreads();

    for (int c = 0; c < NC; ++c) {
        const int cur = c & 1;
        // ---- register prefetch for chunk c+1 (consumed after MFMA loop) ----
        float4 pa0, pa1, pa2, pa3;
        half8 pb0, pb1;
        if (c < NC - 1) {
            pa0 = *(const float4*)(encR0 + (c + 1) * 32);
            pa1 = *(const float4*)(encR0 + (c + 1) * 32 + 4);
            pa2 = *(const float4*)(encR1 + (c + 1) * 32);
            pa3 = *(const float4*)(encR1 + (c + 1) * 32 + 4);
            const _Float16* bp = whf + (size_t)(c + 1) * 4096 + tid * 16;
            pb0 = *(const half8*)(bp);
            pb1 = *(const half8*)(bp + 8);
        }

        // ---- LDS frag reads (lane-linear 16 B/lane, conflict-free) ----
        half8 ah[4], al[4], bh[4];
#pragma unroll
        for (int mi = 0; mi < 4; ++mi) {
            const int mt = wr * 4 + mi;
            ah[mi] = *(const half8*)(&Ahi[cur][(mt * 64 + L) * 8]);
            al[mi] = *(const half8*)(&Alo[cur][(mt * 64 + L) * 8]);
        }
#pragma unroll
        for (int gi = 0; gi < 4; ++gi) {
            const int gt = wc * 4 + gi;
            bh[gi] = *(const half8*)(&Bh[cur][(gt * 64 + L) * 8]);
        }

        // ---- 32 MFMAs (2 products per 16x16 tile) ----
#pragma unroll
        for (int mi = 0; mi < 4; ++mi)
#pragma unroll
            for (int gi = 0; gi < 4; ++gi) {
                acc[mi][gi] = __builtin_amdgcn_mfma_f32_16x16x32_f16(ah[mi], bh[gi], acc[mi][gi], 0, 0, 0);
                acc[mi][gi] = __builtin_amdgcn_mfma_f32_16x16x32_f16(al[mi], bh[gi], acc[mi][gi], 0, 0, 0);
            }

        // ---- write prefetched chunk c+1 into the other buffer ----
        if (c < NC - 1) {
            const int nxt = cur ^ 1;
            half8 h, l;
            cvt_split8_f16(pa0, pa1, h, l);
            *(half8*)(&Ahi[nxt][sf0 * 8]) = h;
            *(half8*)(&Alo[nxt][sf0 * 8]) = l;
            cvt_split8_f16(pa2, pa3, h, l);
            *(half8*)(&Ahi[nxt][sf1 * 8]) = h;
            *(half8*)(&Alo[nxt][sf1 * 8]) = l;
            *(half8*)(&Bh[nxt][tid * 16])     = pb0;
            *(half8*)(&Bh[nxt][tid * 16 + 8]) = pb1;
        }
        __syncthreads();
    }

    // ---- epilogue: tanh + Wv partial dot over this wave's 64 u ----
    // C/D layout: col(u) = L&15 (+gt*16), row = (L>>4)*4 + reg
    const int n15 = L & 15;
    float qv[4], wvv[4];
#pragma unroll
    for (int gi = 0; gi < 4; ++gi) {
        const int u = wc * 64 + gi * 16 + n15;
        qv[gi]  = q[b * U_ + u];
        wvv[gi] = Wv[u];
    }
#pragma unroll
    for (int mi = 0; mi < 4; ++mi) {
#pragma unroll
        for (int r = 0; r < 4; ++r) {
            float s = 0.f;
#pragma unroll
            for (int gi = 0; gi < 4; ++gi)
                s += fast_tanh(qv[gi] + acc[mi][gi][r]) * wvv[gi];
            s += __shfl_xor(s, 1, 64);
            s += __shfl_xor(s, 2, 64);
            s += __shfl_xor(s, 4, 64);
            s += __shfl_xor(s, 8, 64);
            if (n15 == 0) {
                const int mrow = wr * 64 + mi * 16 + (L >> 4) * 4 + r;
                sred[wc * MBLK + mrow] = s;
            }
        }
    }
    __syncthreads();

    // combine wave-pair partials, exp, store
    if (tid < MBLK) {
        const float s = sred[tid] + sred[MBLK + tid];
        const float e = __expf(s);
        ew[tid] = e;
        expw[m0 + tid] = e;
    }
    __syncthreads();

    // ---- phase 2: unnormalized context over this block's 128 rows ----
    const int col = tid * 2;
    const float* ebase = enc + (size_t)m0 * ENC_ + col;
    float sx = 0.f, sy = 0.f;
#pragma unroll 8
    for (int t = 0; t < MBLK; ++t) {
        const float wgt = ew[t];                       // LDS broadcast
        const float2 v = *(const float2*)(ebase + (size_t)t * ENC_);
        sx += wgt * v.x;
        sy += wgt * v.y;
    }
    atomicAdd(&uctx[b * ENC_ + col], sx);
    atomicAdd(&uctx[b * ENC_ + col + 1], sy);

    if (tid < 64) {
        float z = ew[tid] + ew[tid + 64];
        z += __shfl_xor(z, 1, 64);
        z += __shfl_xor(z, 2, 64);
        z += __shfl_xor(z, 4, 64);
        z += __shfl_xor(z, 8, 64);
        z += __shfl_xor(z, 16, 64);
        z += __shfl_xor(z, 32, 64);
        if (tid == 0) atomicAdd(&Zsum[b], z);
    }
}

// ---------------------------------------------------------------------------
// Kernel N: normalize — ctx = uctx/Z, attn = expw/Z.
// ---------------------------------------------------------------------------
__global__ void normalize_kernel(const float* __restrict__ uctx,
                                 const float* __restrict__ Zsum,
                                 const float* __restrict__ expw,
                                 float* __restrict__ ctx,
                                 float* __restrict__ attn) {
    const int idx = blockIdx.x * 256 + threadIdx.x;
    if (idx < B_ * ENC_) {
        ctx[idx] = uctx[idx] / Zsum[idx >> 9];        // ENC_ = 512
    } else {
        const int i2 = idx - B_ * ENC_;
        attn[i2] = expw[i2] / Zsum[i2 >> 11];         // T_ = 2048
    }
}

// ---------------------------------------------------------------------------
extern "C" void kernel_launch(void* const* d_in, const int* in_sizes, int n_in,
                              void* d_out, int out_size, void* d_ws, size_t ws_size,
                              hipStream_t stream) {
    const float* dh  = (const float*)d_in[0];  // [64,512]
    const float* enc = (const float*)d_in[1];  // [64,2048,512]
    const float* Wa  = (const float*)d_in[2];  // [512,128]
    const float* ba  = (const float*)d_in[3];  // [128]
    const float* Wb  = (const float*)d_in[4];  // [512,128]
    const float* bb  = (const float*)d_in[5];  // [128]
    const float* Wv  = (const float*)d_in[6];  // [128,1]
    // d_in[7] = bv — cancels in softmax, unused.

    float* out      = (float*)d_out;
    float* ctx      = out;                 // [64,512]
    float* attn_out = out + (B_ * ENC_);   // [64,2048]

    float* ws   = (float*)d_ws;
    float* q    = ws;                              // 8192
    float* expw = ws + 8192;                       // 131072
    float* uctx = ws + 8192 + B_ * T_;             // 32768
    float* Zs   = uctx + B_ * ENC_;                // 64
    _Float16* whf = (_Float16*)(Zs + 64);          // 65536 halfs (128 KB)

    prep_kernel<<<225, 256, 0, stream>>>(dh, Wa, ba, bb, Wb, q, whf, uctx);
    score_ctx_kernel<<<(B_ * T_) / MBLK, 256, 0, stream>>>(enc, whf, q, Wv,
                                                           expw, uctx, Zs);
    normalize_kernel<<<(B_ * (ENC_ + T_)) / 256, 256, 0, stream>>>(uctx, Zs, expw,
                                                                   ctx, attn_out);
}